// Round 1
// 302.098 us; speedup vs baseline: 1.0976x; 1.0976x over previous
//
#include <hip/hip_runtime.h>
#include <hip/hip_bf16.h>
#include <cstdint>
#include <cstddef>

// Problem constants: B=4, N=4096, D=1024, H=16, HD=64
#define NB      4
#define NSEQ    4096
#define DM      1024
#define NTOK    16384          // B*N
#define QKV_N   3072           // 3*D

typedef __attribute__((ext_vector_type(8))) short short8_t;   // 8 x bf16 bits
typedef __attribute__((ext_vector_type(4))) float f32x4;

static __device__ __forceinline__ unsigned short f2bf(float f) {
    unsigned u = __builtin_bit_cast(unsigned, f);
    u += 0x7fffu + ((u >> 16) & 1u);          // RNE
    return (unsigned short)(u >> 16);
}

static __device__ __forceinline__ void async16(const void* g, void* l) {
    __builtin_amdgcn_global_load_lds(
        (const __attribute__((address_space(1))) void*)g,
        (__attribute__((address_space(3))) void*)l, 16, 0, 0);
}

// ---------------- fused fp32 -> bf16 convert for all three inputs ----------
__global__ void cvt_all(const float* __restrict__ x,
                        const float* __restrict__ wqkv,
                        const float* __restrict__ wproj,
                        unsigned short* __restrict__ xb,
                        unsigned short* __restrict__ wqkvb,
                        unsigned short* __restrict__ wprojb)
{
    int i = blockIdx.x * blockDim.x + threadIdx.x;
    const float* src; unsigned short* dst; int off;
    if (i < 4194304)      { src = x;     dst = xb;     off = i; }
    else if (i < 4980736) { src = wqkv;  dst = wqkvb;  off = i - 4194304; }
    else                  { src = wproj; dst = wprojb; off = i - 4980736; }
    float4 f = ((const float4*)src)[off];
    unsigned lo = (unsigned)f2bf(f.x) | ((unsigned)f2bf(f.y) << 16);
    unsigned hi = (unsigned)f2bf(f.z) | ((unsigned)f2bf(f.w) << 16);
    ((uint2*)dst)[off] = make_uint2(lo, hi);
}

// ---------------- bf16 GEMM, C[m,n] = sum_k A[m,k]*B[n,k] (+bias) ----------
// 256x256 tile, BK=64, 512 threads = 8 waves (2 M x 4 N), per-wave 128x64 out.
// 8-phase / 2-K-tile schedule with counted vmcnt (T3+T4), st-style XOR LDS
// swizzle (T2: linear global_load_lds dest + pre-swizzled global source,
// chunk ^= row&7 over 128B rows -> 2-way bank alias = free), setprio around
// each 16-MFMA cluster (T5), bijective XCD blockIdx swizzle (T1).
//
// Prefetch/race invariant (region hand-over): K-tile g+2 is staged into the
// SAME buffer being computed (buf[g&1]); each 64-row region is re-staged only
// in a phase strictly after the barrier ending its last read:
//   ph0 reads A-low (A0/A2) + B-left   -> ph1 stages [g+2] A0,A2
//   ph1 reads B-right (B retired)      -> ph2 stages [g+2] B0,B1
//   ph2 reads A-high (A1/A3)           -> ph3 stages [g+2] A1,A3,B2,B3
//   ph3 reads nothing (regs only)      -> end-of-group s_waitcnt vmcnt(8)
// At the group-end wait the 8 outstanding loads are exactly [g+2]'s (not
// needed until group g+2), so every load gets ~5 phases of latency cover.
template <bool BF16_OUT, bool BIAS>
__global__ __launch_bounds__(512, 2)
void gemm256(const unsigned short* __restrict__ A,
             const unsigned short* __restrict__ Bm,
             void* __restrict__ Cv,
             const float* __restrict__ bias,
             int M, int N, int K)
{
    __shared__ alignas(16) unsigned short As[2][16384];   // 2 x 256 x 64
    __shared__ alignas(16) unsigned short Bs[2][16384];   // 128 KiB total

    const int t    = threadIdx.x;
    const int lane = t & 63;
    const int wave = t >> 6;
    const int quad = lane >> 4;
    const int r16  = lane & 15;
    const int wm   = wave >> 2;      // 0..1
    const int wn   = wave & 3;       // 0..3

    // T1: bijective XCD swizzle (grid sizes here are multiples of 8).
    const int nwg = gridDim.x;
    const int swz = (blockIdx.x & 7) * (nwg >> 3) + (blockIdx.x >> 3);
    const int ntn = N >> 8;
    const int tm  = swz / ntn, tn = swz - tm * ntn;   // tm-major: XCD chunk shares A panels
    const int m0  = tm << 8, n0 = tn << 8;

    // Staging: thread t covers row t>>3 of a 64-row region, 16B chunk t&7.
    // Source chunk is XOR-pre-swizzled so the linear LDS dest + swizzled read
    // form the same involution (chunk' = chunk ^ (row&7)).
    const int srow = t >> 3;
    const int schk = ((t & 7) ^ (srow & 7)) << 3;   // element offset in row
    const unsigned short* gA = A  + (size_t)(m0 + srow) * K + schk;
    const unsigned short* gB = Bm + (size_t)(n0 + srow) * K + schk;
    unsigned short* const lA = &As[0][0] + t * 8;
    unsigned short* const lB = &Bs[0][0] + t * 8;

    const int NT = K >> 6;           // 64-wide K-tiles (16 here)

#define STA(buf, kt, r) async16(gA + (size_t)(r) * 64 * K + (size_t)(kt) * 64, \
                                lA + (buf) * 16384 + (r) * 4096)
#define STB(buf, kt, r) async16(gB + (size_t)(r) * 64 * K + (size_t)(kt) * 64, \
                                lB + (buf) * 16384 + (r) * 4096)

    // Read-side swizzled chunk offsets (elements) for k-steps s=0,1.
    const int cs0 = ((quad    ) ^ (r16 & 7)) << 3;
    const int cs1 = ((quad ^ 4) ^ (r16 & 7)) << 3;
    const int aRow = wm * 128 + r16;
    const int bRow = wn * 64  + r16;

    f32x4 acc[8][4] = {};

    // Prologue: K-tiles 0 and 1 fully staged; tile-1's 8 loads left in flight.
    STA(0,0,0); STA(0,0,1); STA(0,0,2); STA(0,0,3);
    STB(0,0,0); STB(0,0,1); STB(0,0,2); STB(0,0,3);
    STA(1,1,0); STA(1,1,1); STA(1,1,2); STA(1,1,3);
    STB(1,1,0); STB(1,1,1); STB(1,1,2); STB(1,1,3);
    asm volatile("s_waitcnt vmcnt(8)" ::: "memory");
    __builtin_amdgcn_s_barrier();

#define RD_A(QR) _Pragma("unroll") for (int ii = 0; ii < 4; ++ii) {            \
        a[ii][0] = *(const short8_t*)(Ab + (aRow + (QR)*64 + ii*16) * 64 + cs0); \
        a[ii][1] = *(const short8_t*)(Ab + (aRow + (QR)*64 + ii*16) * 64 + cs1); }
#define RD_B(bb, QC) _Pragma("unroll") for (int jj = 0; jj < 2; ++jj) {        \
        bb[jj][0] = *(const short8_t*)(Bb + (bRow + (QC)*32 + jj*16) * 64 + cs0); \
        bb[jj][1] = *(const short8_t*)(Bb + (bRow + (QC)*32 + jj*16) * 64 + cs1); }
#define MM(QR, QC, bb) _Pragma("unroll") for (int s = 0; s < 2; ++s)           \
      _Pragma("unroll") for (int ii = 0; ii < 4; ++ii)                          \
        _Pragma("unroll") for (int jj = 0; jj < 2; ++jj)                        \
          acc[(QR)*4+ii][(QC)*2+jj] = __builtin_amdgcn_mfma_f32_16x16x32_bf16( \
              a[ii][s], bb[jj][s], acc[(QR)*4+ii][(QC)*2+jj], 0, 0, 0);
#define SYNC_PRE  __builtin_amdgcn_s_barrier();                                \
                  asm volatile("s_waitcnt lgkmcnt(0)" ::: "memory");           \
                  __builtin_amdgcn_sched_barrier(0);                           \
                  __builtin_amdgcn_s_setprio(1);
#define SYNC_POST __builtin_amdgcn_s_setprio(0);                               \
                  __builtin_amdgcn_s_barrier();                                \
                  asm volatile("" ::: "memory");

    for (int g = 0; g < NT; ++g) {
        const int cur = g & 1;
        const unsigned short* Ab = &As[cur][0];
        const unsigned short* Bb = &Bs[cur][0];
        const bool pf = (g + 2 < NT);
        short8_t a[4][2], b0[2][2], b1[2][2];

        // ph0: read A-low + B-left; MFMA quadrant (0,0)
        RD_A(0) RD_B(b0, 0)
        SYNC_PRE
        MM(0, 0, b0)
        SYNC_POST

        // ph1: read B-right; stage [g+2] A0,A2 (A-low retired at ph0)
        RD_B(b1, 1)
        if (pf) { STA(cur, g+2, 0); STA(cur, g+2, 2); }
        SYNC_PRE
        MM(0, 1, b1)
        SYNC_POST

        // ph2: read A-high (overwrite a); stage [g+2] B0,B1 (B retired at ph1)
        RD_A(1)
        if (pf) { STB(cur, g+2, 0); STB(cur, g+2, 1); }
        SYNC_PRE
        MM(1, 0, b0)
        SYNC_POST

        // ph3: registers only; stage [g+2] A1,A3,B2,B3 (A-high retired at ph2)
        if (pf) { STA(cur, g+2, 1); STA(cur, g+2, 3);
                  STB(cur, g+2, 2); STB(cur, g+2, 3); }
        __builtin_amdgcn_s_barrier();
        __builtin_amdgcn_s_setprio(1);
        MM(1, 1, b1)
        __builtin_amdgcn_s_setprio(0);
        if (pf)              asm volatile("s_waitcnt vmcnt(8)" ::: "memory");
        else if (g + 1 < NT) asm volatile("s_waitcnt vmcnt(0)" ::: "memory");
        __builtin_amdgcn_s_barrier();
        asm volatile("" ::: "memory");
    }

#undef STA
#undef STB
#undef RD_A
#undef RD_B
#undef MM
#undef SYNC_PRE
#undef SYNC_POST

    // Epilogue. C/D layout per fragment: col = frag_col_base + r16,
    // row = frag_row_base + quad*4 + reg.
    #pragma unroll
    for (int ri = 0; ri < 8; ++ri) {
        const int row = m0 + wm * 128 + (ri >> 2) * 64 + (ri & 3) * 16 + quad * 4;
        #pragma unroll
        for (int cj = 0; cj < 4; ++cj) {
            const int col = n0 + wn * 64 + (cj >> 1) * 32 + (cj & 1) * 16 + r16;
            float bv = 0.f;
            if constexpr (BIAS) bv = bias[col];
            #pragma unroll
            for (int r = 0; r < 4; ++r) {
                float v = acc[ri][cj][r] + bv;
                if constexpr (BF16_OUT)
                    ((unsigned short*)Cv)[(size_t)(row + r) * N + col] = f2bf(v);
                else
                    ((float*)Cv)[(size_t)(row + r) * N + col] = v;
            }
        }
    }
}

// ---------------- per-token 16-head cross-head attention -------------------
// qkv row (3072 bf16) = [q(16x64) | k(16x64) | v(16x64)], one wave per token.
// S = Q K^T * 0.125 (2 MFMAs), softmax over g, O = P V (4 MFMAs, k padded),
// output written with the swapaxes(1,2).reshape permutation:
//   out[b, h*256 + n/16, (n%16)*64 + hd] = O[h][hd]
__global__ __launch_bounds__(256)
void attn_kernel(const unsigned short* __restrict__ qkv,
                 unsigned short* __restrict__ operm)
{
    __shared__ alignas(16) unsigned short s_qkv[4][QKV_N];   // 24 KB
    __shared__ alignas(16) unsigned short s_p[4][256];       //  2 KB
    __shared__ alignas(16) unsigned short s_o[4][16 * 72];   //  9 KB
    const int t     = threadIdx.x;
    const int lane  = t & 63;
    const int wave  = t >> 6;
    const int quad  = lane >> 4;
    const int r16   = lane & 15;
    const int token = blockIdx.x * 4 + wave;

    { // async stage 3072 bf16 = 384 x 16B chunks, 6 per lane
        const unsigned short* src = qkv + (size_t)token * QKV_N;
        #pragma unroll
        for (int i = 0; i < 6; ++i)
            async16(src + i * 512 + lane * 8, &s_qkv[wave][i * 512 + lane * 8]);
    }
    __syncthreads();

    const unsigned short* q  = &s_qkv[wave][0];
    const unsigned short* kk = q + 1024;
    const unsigned short* vv = q + 2048;

    // S = Q K^T : A rows = q heads (m=h), B rows = k heads (n=g)
    f32x4 s = {};
    #pragma unroll
    for (int c = 0; c < 64; c += 32) {
        short8_t aq = *(const short8_t*)(q  + r16 * 64 + c + quad * 8);
        short8_t bk = *(const short8_t*)(kk + r16 * 64 + c + quad * 8);
        s = __builtin_amdgcn_mfma_f32_16x16x32_bf16(aq, bk, s, 0, 0, 0);
    }

    // softmax over g (= col = r16 lanes within each quad group), per reg
    #pragma unroll
    for (int r = 0; r < 4; ++r) {
        float x = s[r] * 0.125f;                 // HD^-0.5
        float m = x;
        #pragma unroll
        for (int o = 1; o < 16; o <<= 1) m = fmaxf(m, __shfl_xor(m, o));
        float e = __expf(x - m);
        float su = e;
        #pragma unroll
        for (int o = 1; o < 16; o <<= 1) su += __shfl_xor(su, o);
        s_p[wave][(quad * 4 + r) * 16 + r16] = f2bf(e * __builtin_amdgcn_rcpf(su));
    }
    __syncthreads();

    // P as A-operand: A[m=r16][k=quad*8+e], k=16..31 zero-padded
    short8_t pa = {};
    if (quad < 2) pa = *(const short8_t*)(&s_p[wave][r16 * 16 + quad * 8]);

    f32x4 o[4];
    #pragma unroll
    for (int j = 0; j < 4; ++j) {
        // B-operand: B[n=d][k=g] = V[g][d], transposed LDS reads (2-way = free)
        short8_t vb = {};
        if (quad < 2) {
            #pragma unroll
            for (int e = 0; e < 8; ++e)
                vb[e] = (short)vv[(quad * 8 + e) * 64 + j * 16 + r16];
        }
        f32x4 z = {};
        o[j] = __builtin_amdgcn_mfma_f32_16x16x32_bf16(pa, vb, z, 0, 0, 0);
    }

    // O (C-layout) -> LDS (stride 72) -> coalesced 16B stores
    #pragma unroll
    for (int j = 0; j < 4; ++j)
        #pragma unroll
        for (int r = 0; r < 4; ++r)
            s_o[wave][(quad * 4 + r) * 72 + j * 16 + r16] = f2bf(o[j][r]);
    __syncthreads();

    const int b    = token >> 12;
    const int npos = token & 4095;
    const size_t base = (size_t)b * (NSEQ * DM)
                      + (size_t)(npos >> 4) * 1024
                      + (size_t)(npos & 15) * 64;
    #pragma unroll
    for (int c = lane; c < 128; c += 64) {
        const int h = c >> 3, part = c & 7;   // 16 rows x 8 chunks of 16B
        int4 val = *(const int4*)(&s_o[wave][h * 72 + part * 8]);
        *(int4*)(operm + base + (size_t)h * (256 * 1024) + part * 8) = val;
    }
}

// ---------------------------------------------------------------------------
extern "C" void kernel_launch(void* const* d_in, const int* in_sizes, int n_in,
                              void* d_out, int out_size, void* d_ws, size_t ws_size,
                              hipStream_t stream)
{
    const float* x      = (const float*)d_in[0];   // 16384 x 1024
    const float* w_qkv  = (const float*)d_in[1];   // 3072 x 1024
    const float* w_proj = (const float*)d_in[2];   // 1024 x 1024
    const float* b_proj = (const float*)d_in[3];   // 1024
    float* out = (float*)d_out;                    // 16384 x 1024 fp32

    unsigned short* xb     = (unsigned short*)d_ws;            // 16,777,216
    unsigned short* wqkvb  = xb     + (size_t)16777216;        //  3,145,728
    unsigned short* wprojb = wqkvb  + (size_t)3145728;         //  1,048,576
    unsigned short* qkvb   = wprojb + (size_t)1048576;         // 50,331,648
    unsigned short* opermb = qkvb   + (size_t)50331648;        // 16,777,216

    cvt_all<<<20480, 256, 0, stream>>>(x, w_qkv, w_proj, xb, wqkvb, wprojb);

    // QKV: M=16384, N=3072, K=1024 -> (64 x 12) = 768 tiles
    gemm256<true, false><<<768, 512, 0, stream>>>(xb, wqkvb, qkvb, nullptr,
                                                  NTOK, QKV_N, DM);

    attn_kernel<<<NTOK / 4, 256, 0, stream>>>(qkvb, opermb);

    // proj: M=16384, N=1024, K=1024 -> (64 x 4) = 256 tiles
    gemm256<false, true><<<256, 512, 0, stream>>>(opermb, wprojb, out, b_proj,
                                                  NTOK, DM, DM);
}